// Round 1
// baseline (186.624 us; speedup 1.0000x reference)
//
#include <hip/hip_runtime.h>
#include <math.h>

typedef __attribute__((ext_vector_type(8))) short bf16x8;
typedef __attribute__((ext_vector_type(16))) float f32x16;

#define WIN 512
#define META 4
#define KSTR 136   // Ks row stride (shorts): b128 frag reads
#define VSTR 72    // Vts row stride (shorts): b128 frag reads
// Q pre-scale folds 1/sqrt(128) AND log2(e): p = exp2(s' - MFIX2) == exp(s/sqrt(D) - 14)
#define QSCALE (0.08838834764831845f * 1.4426950408889634f)
#define MFIX2 20.197730572445487f   // 14 * log2(e)

union U8 { int4 i4; bf16x8 bf; };

static __device__ __forceinline__ unsigned bf16_rne(float x) {
  unsigned u = __float_as_uint(x);
  return (u + 0x7FFFu + ((u >> 16) & 1u)) >> 16;
}
static __device__ __forceinline__ unsigned pk2_rne(float a, float b) {
  return bf16_rne(a) | (bf16_rne(b) << 16);
}
static __device__ __forceinline__ unsigned pk2_tr(float a, float b) {   // truncate
  return (__float_as_uint(a) >> 16) | (__float_as_uint(b) & 0xFFFF0000u);
}

// Fused flash attention, S^T formulation (P stays in registers).
// Round 1 change: LDS double-buffered (Ks[2]/Vts[2]) -> ONE __syncthreads per tile.
//   Safety: barrier at end of iter t separates reads-of-buf[(t+1)&1] at t-1 from the
//   writes at t, and those writes from reads at t+1. Stage-writes now overlap other
//   waves' compute instead of being lockstep-sandwiched between two barriers.
// Grid 1D 512; hk = bid&7 so each XCD (round-robin) reuses one KV head's K/V in its L2.
__global__ __launch_bounds__(256, 2) void swa_fused(
    const float* __restrict__ Qg, const float* __restrict__ Kg,
    const float* __restrict__ Vg, float* __restrict__ Og)
{
  __shared__ __align__(16) unsigned short Ks[2][64 * KSTR];    // 2 x 17408 B
  __shared__ __align__(16) unsigned short Vts[2][128 * VSTR];  // 2 x 18432 B

  const int tid = threadIdx.x;
  const int lane = tid & 63, wid = tid >> 6;
  const int cl = lane & 31, hl = lane >> 5;
  const int bid = blockIdx.x;
  const int hk = bid & 7;                    // XCD-aligned KV head
  const int bq = bid >> 3;
  const int qtile = (bq & 1) ? (63 - (bq >> 1)) : (bq >> 1);   // light/heavy pairing
  const int q0 = qtile * 32;
  const int h = hk * 4 + wid;                // this wave's q-head

  // K staging coords
  const int sh = tid >> 5;              // 0..7
  const int sc = (tid & 31) * 4;        // float col 0..124
  // V staging coords: thread owns key-quad kq (keys 4kq..4kq+3), dims dg*8..+7
  const int dg = tid & 15;
  const int kq = tid >> 4;
  const int vchunk = 2 * (kq >> 2) + (kq & 1);   // chunk (8 slots) 0..7
  const int vhalf  = (kq >> 1) & 1;              // b64 half within chunk

  // ---- Q B-fragments from global (once per wave; RNE, pre-scaled) ----
  int4 qf[8];
  {
    const float* qrow = Qg + (size_t)(q0 + cl) * 4096 + h * 128 + hl * 8;
    #pragma unroll
    for (int kc = 0; kc < 8; ++kc) {
      float4 x = *(const float4*)(qrow + kc * 16);
      float4 y = *(const float4*)(qrow + kc * 16 + 4);
      qf[kc] = make_int4(pk2_rne(x.x*QSCALE, x.y*QSCALE), pk2_rne(x.z*QSCALE, x.w*QSCALE),
                         pk2_rne(y.x*QSCALE, y.y*QSCALE), pk2_rne(y.z*QSCALE, y.w*QSCALE));
    }
  }

  f32x16 acc[4];
  #pragma unroll
  for (int nt = 0; nt < 4; ++nt)
    #pragma unroll
    for (int i = 0; i < 16; ++i) acc[nt][i] = 0.f;
  float lpA = 0.f, lpB = 0.f;   // two accumulators: halves serial f32 add chain

  const int jstart = (q0 > WIN) ? ((q0 - WIN) & ~63) : 0;
  const int sink = (jstart > 0) ? 1 : 0;
  const int niter = ((q0 + 31 - jstart) >> 6) + 1 + sink;

  // ---- prefetch tile 0 into registers ----
  float4 kreg[8], vreg[8];
  {
    const int jt0 = sink ? 0 : jstart;
    const float* kb = Kg + (size_t)jt0 * 1024 + hk * 128 + sc;
    #pragma unroll
    for (int it = 0; it < 8; ++it)
      kreg[it] = *(const float4*)(kb + (size_t)(it * 8 + sh) * 1024);
    const float* vb = Vg + (size_t)jt0 * 1024 + hk * 128 + dg * 8;
    #pragma unroll
    for (int i = 0; i < 4; ++i) {
      vreg[2*i]   = *(const float4*)(vb + (size_t)(4 * kq + i) * 1024);
      vreg[2*i+1] = *(const float4*)(vb + (size_t)(4 * kq + i) * 1024 + 4);
    }
  }
  // ---- write tile 0 into buffer 0 ----
  {
    #pragma unroll
    for (int it = 0; it < 8; ++it) {
      float4 v = kreg[it];
      *(uint2*)(&Ks[0][(it * 8 + sh) * KSTR + sc]) =
          make_uint2(pk2_tr(v.x, v.y), pk2_tr(v.z, v.w));
    }
    #pragma unroll
    for (int e = 0; e < 8; ++e) {
      const int d = dg * 8 + e;
      const int half = e >> 2, c = e & 3;
      const float* f0 = (const float*)&vreg[0 + half];
      const float* f1 = (const float*)&vreg[2 + half];
      const float* f2 = (const float*)&vreg[4 + half];
      const float* f3 = (const float*)&vreg[6 + half];
      *(uint2*)(&Vts[0][d * VSTR + ((vchunk ^ (dg & 7)) << 3) + (vhalf << 2)]) =
          make_uint2(pk2_tr(f0[c], f1[c]), pk2_tr(f2[c], f3[c]));
    }
  }
  __syncthreads();   // buffer 0 staged

  for (int t = 0; t < niter; ++t) {
    const bool isSink = (sink != 0) && (t == 0);
    const int jt = isSink ? 0 : jstart + ((t - sink) << 6);
    const bool needMask = (jt + 63 > q0) || (q0 + 31 - jt > WIN);
    const int cb = t & 1;

    // ---- issue next-tile prefetch (drains under this tile's compute) ----
    if (t + 1 < niter) {
      const int jn = jstart + ((t + 1 - sink) << 6);
      const float* kb = Kg + (size_t)jn * 1024 + hk * 128 + sc;
      #pragma unroll
      for (int it = 0; it < 8; ++it)
        kreg[it] = *(const float4*)(kb + (size_t)(it * 8 + sh) * 1024);
      const float* vb = Vg + (size_t)jn * 1024 + hk * 128 + dg * 8;
      #pragma unroll
      for (int i = 0; i < 4; ++i) {
        vreg[2*i]   = *(const float4*)(vb + (size_t)(4 * kq + i) * 1024);
        vreg[2*i+1] = *(const float4*)(vb + (size_t)(4 * kq + i) * 1024 + 4);
      }
    }

    const unsigned short* Kb = Ks[cb];
    const unsigned short* Vb = Vts[cb];

    // ---- S^T = K·Q^T (A=K from LDS b128, B=Q regs) ----
    f32x16 s0v, s1v;
    #pragma unroll
    for (int i = 0; i < 16; ++i) { s0v[i] = 0.f; s1v[i] = 0.f; }
    if (isSink) {
      #pragma unroll
      for (int kc = 0; kc < 8; ++kc) {
        U8 b; b.i4 = qf[kc];
        U8 a0; a0.i4 = *(const int4*)(Kb + cl * KSTR + kc * 16 + hl * 8);
        s0v = __builtin_amdgcn_mfma_f32_32x32x16_bf16(a0.bf, b.bf, s0v, 0, 0, 0);
      }
    } else {
      #pragma unroll
      for (int kc = 0; kc < 8; ++kc) {
        U8 b; b.i4 = qf[kc];
        U8 a0; a0.i4 = *(const int4*)(Kb + cl * KSTR + kc * 16 + hl * 8);
        s0v = __builtin_amdgcn_mfma_f32_32x32x16_bf16(a0.bf, b.bf, s0v, 0, 0, 0);
        U8 a1; a1.i4 = *(const int4*)(Kb + (32 + cl) * KSTR + kc * 16 + hl * 8);
        s1v = __builtin_amdgcn_mfma_f32_32x32x16_bf16(a1.bf, b.bf, s1v, 0, 0, 0);
      }
    }

    // ---- softmax (fixed max): p = exp2(s' - 14*log2e), bf16-truncated ----
    unsigned pu0[16], pu1[16];
    const int q = q0 + cl;
    #pragma unroll
    for (int ri = 0; ri < 16; ++ri) {
      const int koff = (ri & 3) + 8 * (ri >> 2) + 4 * hl;
      bool ok0 = true, ok1 = true;
      if (needMask) {
        const int k0v = jt + koff, k1v = jt + 32 + koff;
        ok0 = (q >= k0v) && (((q - k0v) <= WIN) || (k0v < META));
        ok1 = (q >= k1v) && (((q - k1v) <= WIN) || (k1v < META));
      }
      unsigned u0 = ok0 ? (__float_as_uint(__builtin_amdgcn_exp2f(s0v[ri] - MFIX2)) & 0xFFFF0000u) : 0u;
      pu0[ri] = u0;
      lpA += __uint_as_float(u0);
      if (!isSink) {
        unsigned u1 = ok1 ? (__float_as_uint(__builtin_amdgcn_exp2f(s1v[ri] - MFIX2)) & 0xFFFF0000u) : 0u;
        pu1[ri] = u1;
        lpB += __uint_as_float(u1);
      }
    }

    // ---- PV: A = P assembled from registers (contraction order = Vts slot order) ----
    #define MKA(P, o) make_int4((P[(o)] >> 16) | P[(o)+1], (P[(o)+2] >> 16) | P[(o)+3], \
                                (P[(o)+4] >> 16) | P[(o)+5], (P[(o)+6] >> 16) | P[(o)+7])
    const int kcmax = isSink ? 1 : 4;    // sink: only keys 0..15 group can be nonzero
    for (int kc = 0; kc < kcmax; ++kc) {
      U8 a;
      a.i4 = (kc == 0) ? MKA(pu0, 0) : (kc == 1) ? MKA(pu0, 8)
           : (kc == 2) ? MKA(pu1, 0) : MKA(pu1, 8);
      #pragma unroll
      for (int nt = 0; nt < 4; ++nt) {
        const int dim = nt * 32 + cl;
        U8 b; b.i4 = *(const int4*)(Vb + dim * VSTR + (((2 * kc + hl) ^ ((dim >> 3) & 7)) << 3));
        acc[nt] = __builtin_amdgcn_mfma_f32_32x32x16_bf16(a.bf, b.bf, acc[nt], 0, 0, 0);
      }
    }
    #undef MKA

    // ---- write prefetched tile into the OTHER buffer; single barrier per tile ----
    if (t + 1 < niter) {
      unsigned short* Kw = Ks[cb ^ 1];
      unsigned short* Vw = Vts[cb ^ 1];
      #pragma unroll
      for (int it = 0; it < 8; ++it) {
        float4 v = kreg[it];
        *(uint2*)(Kw + (it * 8 + sh) * KSTR + sc) =
            make_uint2(pk2_tr(v.x, v.y), pk2_tr(v.z, v.w));
      }
      #pragma unroll
      for (int e = 0; e < 8; ++e) {
        const int d = dg * 8 + e;
        const int half = e >> 2, c = e & 3;
        const float* f0 = (const float*)&vreg[0 + half];
        const float* f1 = (const float*)&vreg[2 + half];
        const float* f2 = (const float*)&vreg[4 + half];
        const float* f3 = (const float*)&vreg[6 + half];
        *(uint2*)(Vw + d * VSTR + ((vchunk ^ (dg & 7)) << 3) + (vhalf << 2)) =
            make_uint2(pk2_tr(f0[c], f1[c]), pk2_tr(f2[c], f3[c]));
      }
      __syncthreads();
    }
  }

  // ---- epilogue: l = own + partner-half partial; broadcast per q-row; store ----
  const float lp = lpA + lpB;
  const float ltot = lp + __shfl_xor(lp, 32);
  const float inv = __fdividef(1.0f, ltot);      // valid at lanes with cl = q-row
  #pragma unroll
  for (int ri = 0; ri < 16; ++ri) {
    const int rl = (ri & 3) + 8 * (ri >> 2) + 4 * hl;
    const float invq = __shfl(inv, rl, 64);      // lane rl holds 1/l for q-row rl
    #pragma unroll
    for (int nt = 0; nt < 4; ++nt) {
      Og[(size_t)(q0 + rl) * 4096 + h * 128 + nt * 32 + cl] = acc[nt][ri] * invq;
    }
  }
}

extern "C" void kernel_launch(void* const* d_in, const int* in_sizes, int n_in,
                              void* d_out, int out_size, void* d_ws, size_t ws_size,
                              hipStream_t stream) {
  const float* Q = (const float*)d_in[0];
  const float* K = (const float*)d_in[1];
  const float* V = (const float*)d_in[2];
  float* O = (float*)d_out;
  hipLaunchKernelGGL(swa_fused, dim3(512), dim3(256), 0, stream, Q, K, V, O);
}

// Round 2
// 124.657 us; speedup vs baseline: 1.4971x; 1.4971x over previous
//
#include <hip/hip_runtime.h>
#include <math.h>

typedef __attribute__((ext_vector_type(8))) short bf16x8;
typedef __attribute__((ext_vector_type(16))) float f32x16;

#define WIN 512
#define META 4
#define KSTR 136   // Ks row stride (shorts): b128 frag reads
#define VSTR 72    // Vts row stride (shorts): b128 frag reads
// Q pre-scale folds 1/sqrt(128) AND log2(e): p = exp2(s' - MFIX2) == exp(s/sqrt(D) - 14)
#define QSCALE (0.08838834764831845f * 1.4426950408889634f)
#define MFIX2 20.197730572445487f   // 14 * log2(e)

union U8 { int4 i4; bf16x8 bf; };

static __device__ __forceinline__ unsigned bf16_rne(float x) {
  unsigned u = __float_as_uint(x);
  return (u + 0x7FFFu + ((u >> 16) & 1u)) >> 16;
}
static __device__ __forceinline__ unsigned pk2_rne(float a, float b) {
  return bf16_rne(a) | (bf16_rne(b) << 16);
}
static __device__ __forceinline__ unsigned pk2_tr(float a, float b) {   // truncate
  return (__float_as_uint(a) >> 16) | (__float_as_uint(b) & 0xFFFF0000u);
}

// Fused flash attention, S^T formulation (P stays in registers).
// Round 2: double-buffered LDS with WRITE-AT-TOP ordering -> ONE barrier per tile,
// keeping round-0's liveness (kreg consumed at top of next iter, so the scheduler
// can sink prefetch issues under pressure -- round 1's write-at-bottom spilled).
//   Safety: compute(t-1) reads buf[(t-1)&1] != buf[t&1] being written; barrier(t)
//   separates write(t) from compute(t); syncthreads' lgkmcnt(0) drain means any
//   wave past barrier(t+1) has completed its compute(t) reads of buf[t&1] before
//   anyone reaches write(t+2) on that buffer.
// Grid 1D 512; hk = bid&7 so each XCD (round-robin) reuses one KV head's K/V in its L2.
__global__ __launch_bounds__(256, 2) void swa_fused(
    const float* __restrict__ Qg, const float* __restrict__ Kg,
    const float* __restrict__ Vg, float* __restrict__ Og)
{
  __shared__ __align__(16) unsigned short Ks[2][64 * KSTR];    // 2 x 17408 B
  __shared__ __align__(16) unsigned short Vts[2][128 * VSTR];  // 2 x 18432 B

  const int tid = threadIdx.x;
  const int lane = tid & 63, wid = tid >> 6;
  const int cl = lane & 31, hl = lane >> 5;
  const int bid = blockIdx.x;
  const int hk = bid & 7;                    // XCD-aligned KV head
  const int bq = bid >> 3;
  const int qtile = (bq & 1) ? (63 - (bq >> 1)) : (bq >> 1);   // light/heavy pairing
  const int q0 = qtile * 32;
  const int h = hk * 4 + wid;                // this wave's q-head

  // K staging coords
  const int sh = tid >> 5;              // 0..7
  const int sc = (tid & 31) * 4;        // float col 0..124
  // V staging coords: thread owns key-quad kq (keys 4kq..4kq+3), dims dg*8..+7
  const int dg = tid & 15;
  const int kq = tid >> 4;
  const int vchunk = 2 * (kq >> 2) + (kq & 1);   // chunk (8 slots) 0..7
  const int vhalf  = (kq >> 1) & 1;              // b64 half within chunk

  // ---- Q B-fragments from global (once per wave; RNE, pre-scaled) ----
  int4 qf[8];
  {
    const float* qrow = Qg + (size_t)(q0 + cl) * 4096 + h * 128 + hl * 8;
    #pragma unroll
    for (int kc = 0; kc < 8; ++kc) {
      float4 x = *(const float4*)(qrow + kc * 16);
      float4 y = *(const float4*)(qrow + kc * 16 + 4);
      qf[kc] = make_int4(pk2_rne(x.x*QSCALE, x.y*QSCALE), pk2_rne(x.z*QSCALE, x.w*QSCALE),
                         pk2_rne(y.x*QSCALE, y.y*QSCALE), pk2_rne(y.z*QSCALE, y.w*QSCALE));
    }
  }

  f32x16 acc[4];
  #pragma unroll
  for (int nt = 0; nt < 4; ++nt)
    #pragma unroll
    for (int i = 0; i < 16; ++i) acc[nt][i] = 0.f;
  float lpA = 0.f, lpB = 0.f;   // two accumulators: halves serial f32 add chain

  const int jstart = (q0 > WIN) ? ((q0 - WIN) & ~63) : 0;
  const int sink = (jstart > 0) ? 1 : 0;
  const int niter = ((q0 + 31 - jstart) >> 6) + 1 + sink;

  // ---- prefetch tile 0 into registers ----
  float4 kreg[8], vreg[8];
  {
    const int jt0 = sink ? 0 : jstart;
    const float* kb = Kg + (size_t)jt0 * 1024 + hk * 128 + sc;
    #pragma unroll
    for (int it = 0; it < 8; ++it)
      kreg[it] = *(const float4*)(kb + (size_t)(it * 8 + sh) * 1024);
    const float* vb = Vg + (size_t)jt0 * 1024 + hk * 128 + dg * 8;
    #pragma unroll
    for (int i = 0; i < 4; ++i) {
      vreg[2*i]   = *(const float4*)(vb + (size_t)(4 * kq + i) * 1024);
      vreg[2*i+1] = *(const float4*)(vb + (size_t)(4 * kq + i) * 1024 + 4);
    }
  }

  for (int t = 0; t < niter; ++t) {
    const bool isSink = (sink != 0) && (t == 0);
    const int jt = isSink ? 0 : jstart + ((t - sink) << 6);
    const bool needMask = (jt + 63 > q0) || (q0 + 31 - jt > WIN);
    const int cb = t & 1;
    unsigned short* Kb = Ks[cb];
    unsigned short* Vb = Vts[cb];

    // ---- write prefetched K tile to LDS buffer cb ----
    #pragma unroll
    for (int it = 0; it < 8; ++it) {
      float4 v = kreg[it];
      *(uint2*)(Kb + (it * 8 + sh) * KSTR + sc) =
          make_uint2(pk2_tr(v.x, v.y), pk2_tr(v.z, v.w));
    }
    // ---- write prefetched V tile transposed, permuted slot order, swizzled ----
    #pragma unroll
    for (int e = 0; e < 8; ++e) {
      const int d = dg * 8 + e;
      const int half = e >> 2, c = e & 3;
      const float* f0 = (const float*)&vreg[0 + half];   // key 4kq+0
      const float* f1 = (const float*)&vreg[2 + half];   // key 4kq+1
      const float* f2 = (const float*)&vreg[4 + half];   // key 4kq+2
      const float* f3 = (const float*)&vreg[6 + half];   // key 4kq+3
      *(uint2*)(Vb + d * VSTR + ((vchunk ^ (dg & 7)) << 3) + (vhalf << 2)) =
          make_uint2(pk2_tr(f0[c], f1[c]), pk2_tr(f2[c], f3[c]));
    }
    __syncthreads();   // single barrier: writes(cb) visible; laggards done reading cb

    // ---- prefetch next tile into registers (drains under compute) ----
    if (t + 1 < niter) {
      const int jn = jstart + ((t + 1 - sink) << 6);
      const float* kb = Kg + (size_t)jn * 1024 + hk * 128 + sc;
      #pragma unroll
      for (int it = 0; it < 8; ++it)
        kreg[it] = *(const float4*)(kb + (size_t)(it * 8 + sh) * 1024);
      const float* vb = Vg + (size_t)jn * 1024 + hk * 128 + dg * 8;
      #pragma unroll
      for (int i = 0; i < 4; ++i) {
        vreg[2*i]   = *(const float4*)(vb + (size_t)(4 * kq + i) * 1024);
        vreg[2*i+1] = *(const float4*)(vb + (size_t)(4 * kq + i) * 1024 + 4);
      }
    }

    // ---- S^T = K·Q^T (A=K from LDS b128, B=Q regs) ----
    f32x16 s0v, s1v;
    #pragma unroll
    for (int i = 0; i < 16; ++i) { s0v[i] = 0.f; s1v[i] = 0.f; }
    __builtin_amdgcn_s_setprio(1);
    if (isSink) {
      #pragma unroll
      for (int kc = 0; kc < 8; ++kc) {
        U8 b; b.i4 = qf[kc];
        U8 a0; a0.i4 = *(const int4*)(Kb + cl * KSTR + kc * 16 + hl * 8);
        s0v = __builtin_amdgcn_mfma_f32_32x32x16_bf16(a0.bf, b.bf, s0v, 0, 0, 0);
      }
    } else {
      #pragma unroll
      for (int kc = 0; kc < 8; ++kc) {
        U8 b; b.i4 = qf[kc];
        U8 a0; a0.i4 = *(const int4*)(Kb + cl * KSTR + kc * 16 + hl * 8);
        s0v = __builtin_amdgcn_mfma_f32_32x32x16_bf16(a0.bf, b.bf, s0v, 0, 0, 0);
        U8 a1; a1.i4 = *(const int4*)(Kb + (32 + cl) * KSTR + kc * 16 + hl * 8);
        s1v = __builtin_amdgcn_mfma_f32_32x32x16_bf16(a1.bf, b.bf, s1v, 0, 0, 0);
      }
    }
    __builtin_amdgcn_s_setprio(0);

    // ---- softmax (fixed max): p = exp2(s' - 14*log2e), bf16-truncated ----
    unsigned pu0[16], pu1[16];
    const int q = q0 + cl;
    #pragma unroll
    for (int ri = 0; ri < 16; ++ri) {
      const int koff = (ri & 3) + 8 * (ri >> 2) + 4 * hl;
      bool ok0 = true, ok1 = true;
      if (needMask) {
        const int k0v = jt + koff, k1v = jt + 32 + koff;
        ok0 = (q >= k0v) && (((q - k0v) <= WIN) || (k0v < META));
        ok1 = (q >= k1v) && (((q - k1v) <= WIN) || (k1v < META));
      }
      unsigned u0 = ok0 ? (__float_as_uint(__builtin_amdgcn_exp2f(s0v[ri] - MFIX2)) & 0xFFFF0000u) : 0u;
      pu0[ri] = u0;
      lpA += __uint_as_float(u0);
      if (!isSink) {
        unsigned u1 = ok1 ? (__float_as_uint(__builtin_amdgcn_exp2f(s1v[ri] - MFIX2)) & 0xFFFF0000u) : 0u;
        pu1[ri] = u1;
        lpB += __uint_as_float(u1);
      }
    }

    // ---- PV: A = P assembled from registers (contraction order = Vts slot order) ----
    #define MKA(P, o) make_int4((P[(o)] >> 16) | P[(o)+1], (P[(o)+2] >> 16) | P[(o)+3], \
                                (P[(o)+4] >> 16) | P[(o)+5], (P[(o)+6] >> 16) | P[(o)+7])
    const int kcmax = isSink ? 1 : 4;    // sink: only keys 0..15 group can be nonzero
    __builtin_amdgcn_s_setprio(1);
    for (int kc = 0; kc < kcmax; ++kc) {
      U8 a;
      a.i4 = (kc == 0) ? MKA(pu0, 0) : (kc == 1) ? MKA(pu0, 8)
           : (kc == 2) ? MKA(pu1, 0) : MKA(pu1, 8);
      #pragma unroll
      for (int nt = 0; nt < 4; ++nt) {
        const int dim = nt * 32 + cl;
        U8 b; b.i4 = *(const int4*)(Vb + dim * VSTR + (((2 * kc + hl) ^ ((dim >> 3) & 7)) << 3));
        acc[nt] = __builtin_amdgcn_mfma_f32_32x32x16_bf16(a.bf, b.bf, acc[nt], 0, 0, 0);
      }
    }
    __builtin_amdgcn_s_setprio(0);
    #undef MKA
  }

  // ---- epilogue: l = own + partner-half partial; broadcast per q-row; store ----
  const float lp = lpA + lpB;
  const float ltot = lp + __shfl_xor(lp, 32);
  const float inv = __fdividef(1.0f, ltot);      // valid at lanes with cl = q-row
  #pragma unroll
  for (int ri = 0; ri < 16; ++ri) {
    const int rl = (ri & 3) + 8 * (ri >> 2) + 4 * hl;
    const float invq = __shfl(inv, rl, 64);      // lane rl holds 1/l for q-row rl
    #pragma unroll
    for (int nt = 0; nt < 4; ++nt) {
      Og[(size_t)(q0 + rl) * 4096 + h * 128 + nt * 32 + cl] = acc[nt][ri] * invq;
    }
  }
}

extern "C" void kernel_launch(void* const* d_in, const int* in_sizes, int n_in,
                              void* d_out, int out_size, void* d_ws, size_t ws_size,
                              hipStream_t stream) {
  const float* Q = (const float*)d_in[0];
  const float* K = (const float*)d_in[1];
  const float* V = (const float*)d_in[2];
  float* O = (float*)d_out;
  hipLaunchKernelGGL(swa_fused, dim3(512), dim3(256), 0, stream, Q, K, V, O);
}

// Round 3
// 122.223 us; speedup vs baseline: 1.5269x; 1.0199x over previous
//
#include <hip/hip_runtime.h>
#include <math.h>

typedef __attribute__((ext_vector_type(8))) short bf16x8;
typedef __attribute__((ext_vector_type(16))) float f32x16;

#define WIN 512
#define META 4
#define KSTR 136   // Ks row stride (shorts): b128 frag reads
#define VSTR 72    // Vts row stride (shorts): b128 frag reads
// Q pre-scale folds 1/sqrt(128) AND log2(e): p = exp2(s' - MFIX2) == exp(s/sqrt(D) - 14)
#define QSCALE (0.08838834764831845f * 1.4426950408889634f)
#define MFIX2 20.197730572445487f   // 14 * log2(e)

union U8 { int4 i4; bf16x8 bf; };

static __device__ __forceinline__ unsigned bf16_rne(float x) {
  unsigned u = __float_as_uint(x);
  return (u + 0x7FFFu + ((u >> 16) & 1u)) >> 16;
}
static __device__ __forceinline__ unsigned pk2_rne(float a, float b) {
  return bf16_rne(a) | (bf16_rne(b) << 16);
}
static __device__ __forceinline__ unsigned pk2_tr(float a, float b) {   // truncate
  return (__float_as_uint(a) >> 16) | (__float_as_uint(b) & 0xFFFF0000u);
}

// Fused flash attention, S^T formulation (P stays in registers).
// Round 3: QBLK=64, 512-thread block, grid 256 (= 1 block/CU, 32/XCD).
//   8 waves = 2 per q-head: wave w -> head hk*4+(w&3), q-rows q0+32*(w>>2)..+31.
//   Per-wave per-iter work identical to round 2 (32q x 64k), but each staged K/V
//   tile serves 64 q-rows (staging + K/V fetch halves per unit work) and the wall
//   drops from ~21 co-resident block-iters (parity-broken pairing) to <=10.
// Keeps round-2 schedule: double-buffered LDS, write-at-top, ONE barrier per tile.
__global__ __launch_bounds__(512, 2) void swa_fused(
    const float* __restrict__ Qg, const float* __restrict__ Kg,
    const float* __restrict__ Vg, float* __restrict__ Og)
{
  __shared__ __align__(16) unsigned short Ks[2][64 * KSTR];    // 2 x 17408 B
  __shared__ __align__(16) unsigned short Vts[2][128 * VSTR];  // 2 x 18432 B

  const int tid = threadIdx.x;
  const int lane = tid & 63, wid = tid >> 6;
  const int cl = lane & 31, hl = lane >> 5;
  const int bid = blockIdx.x;
  const int hk = bid & 7;                    // XCD-aligned KV head
  const int bq = bid >> 3;                   // 0..31
  const int q0 = bq << 6;                    // 64-row q tile
  const int h = hk * 4 + (wid & 3);          // this wave's q-head
  const int qw0 = q0 + ((wid >> 2) << 5);    // this wave's 32-row half

  // K staging coords (512 threads stage 64x128 K tile: 4 float4 each)
  const int ksh = tid >> 5;             // 0..15
  const int ksc = (tid & 31) * 4;       // float col 0..124
  // V staging coords: thread owns key-quad kq (keys 4kq..4kq+3), dims dgv*4..+3
  const int dgv = tid & 31;
  const int kq = tid >> 5;                       // 0..15
  const int vchunk = 2 * (kq >> 2) + (kq & 1);   // chunk (8 slots) 0..7
  const int vhalf  = (kq >> 1) & 1;              // b64 half within chunk
  const int vxor   = (dgv >> 1) & 7;             // == (d>>3)&7 for d = dgv*4+e, e<4

  // ---- Q B-fragments from global (once per wave; RNE, pre-scaled) ----
  int4 qf[8];
  {
    const float* qrow = Qg + (size_t)(qw0 + cl) * 4096 + h * 128 + hl * 8;
    #pragma unroll
    for (int kc = 0; kc < 8; ++kc) {
      float4 x = *(const float4*)(qrow + kc * 16);
      float4 y = *(const float4*)(qrow + kc * 16 + 4);
      qf[kc] = make_int4(pk2_rne(x.x*QSCALE, x.y*QSCALE), pk2_rne(x.z*QSCALE, x.w*QSCALE),
                         pk2_rne(y.x*QSCALE, y.y*QSCALE), pk2_rne(y.z*QSCALE, y.w*QSCALE));
    }
  }

  f32x16 acc[4];
  #pragma unroll
  for (int nt = 0; nt < 4; ++nt)
    #pragma unroll
    for (int i = 0; i < 16; ++i) acc[nt][i] = 0.f;
  float lpA = 0.f, lpB = 0.f;   // two accumulators: halves serial f32 add chain

  const int jstart = (q0 > WIN) ? ((q0 - WIN) & ~63) : 0;
  const int sink = (jstart > 0) ? 1 : 0;
  const int niter = ((q0 + 63 - jstart) >> 6) + 1 + sink;

  // ---- prefetch tile 0 into registers ----
  float4 kreg[4], vreg[4];
  {
    const int jt0 = sink ? 0 : jstart;
    const float* kb = Kg + (size_t)jt0 * 1024 + hk * 128 + ksc;
    #pragma unroll
    for (int it = 0; it < 4; ++it)
      kreg[it] = *(const float4*)(kb + (size_t)(it * 16 + ksh) * 1024);
    const float* vb = Vg + (size_t)jt0 * 1024 + hk * 128 + dgv * 4;
    #pragma unroll
    for (int i = 0; i < 4; ++i)
      vreg[i] = *(const float4*)(vb + (size_t)(4 * kq + i) * 1024);
  }

  for (int t = 0; t < niter; ++t) {
    const bool isSink = (sink != 0) && (t == 0);
    const int jt = isSink ? 0 : jstart + ((t - sink) << 6);
    const bool needMask = (jt + 63 > qw0) || (qw0 + 31 - jt > WIN);
    const int cb = t & 1;
    unsigned short* Kb = Ks[cb];
    unsigned short* Vb = Vts[cb];

    // ---- write prefetched K tile to LDS buffer cb ----
    #pragma unroll
    for (int it = 0; it < 4; ++it) {
      float4 v = kreg[it];
      *(uint2*)(Kb + (it * 16 + ksh) * KSTR + ksc) =
          make_uint2(pk2_tr(v.x, v.y), pk2_tr(v.z, v.w));
    }
    // ---- write prefetched V tile transposed, permuted slot order, swizzled ----
    #pragma unroll
    for (int e = 0; e < 4; ++e) {
      const int d = dgv * 4 + e;
      const float* f0 = (const float*)&vreg[0];   // key 4kq+0
      const float* f1 = (const float*)&vreg[1];   // key 4kq+1
      const float* f2 = (const float*)&vreg[2];   // key 4kq+2
      const float* f3 = (const float*)&vreg[3];   // key 4kq+3
      *(uint2*)(Vb + d * VSTR + ((vchunk ^ vxor) << 3) + (vhalf << 2)) =
          make_uint2(pk2_tr(f0[e], f1[e]), pk2_tr(f2[e], f3[e]));
    }
    __syncthreads();   // single barrier: writes(cb) visible; laggards done reading cb

    // ---- prefetch next tile into registers (drains under compute) ----
    if (t + 1 < niter) {
      const int jn = jstart + ((t + 1 - sink) << 6);
      const float* kb = Kg + (size_t)jn * 1024 + hk * 128 + ksc;
      #pragma unroll
      for (int it = 0; it < 4; ++it)
        kreg[it] = *(const float4*)(kb + (size_t)(it * 16 + ksh) * 1024);
      const float* vb = Vg + (size_t)jn * 1024 + hk * 128 + dgv * 4;
      #pragma unroll
      for (int i = 0; i < 4; ++i)
        vreg[i] = *(const float4*)(vb + (size_t)(4 * kq + i) * 1024);
    }

    // ---- S^T = K·Q^T (A=K from LDS b128, B=Q regs) ----
    f32x16 s0v, s1v;
    #pragma unroll
    for (int i = 0; i < 16; ++i) { s0v[i] = 0.f; s1v[i] = 0.f; }
    __builtin_amdgcn_s_setprio(1);
    if (isSink) {
      #pragma unroll
      for (int kc = 0; kc < 8; ++kc) {
        U8 b; b.i4 = qf[kc];
        U8 a0; a0.i4 = *(const int4*)(Kb + cl * KSTR + kc * 16 + hl * 8);
        s0v = __builtin_amdgcn_mfma_f32_32x32x16_bf16(a0.bf, b.bf, s0v, 0, 0, 0);
      }
    } else {
      #pragma unroll
      for (int kc = 0; kc < 8; ++kc) {
        U8 b; b.i4 = qf[kc];
        U8 a0; a0.i4 = *(const int4*)(Kb + cl * KSTR + kc * 16 + hl * 8);
        s0v = __builtin_amdgcn_mfma_f32_32x32x16_bf16(a0.bf, b.bf, s0v, 0, 0, 0);
        U8 a1; a1.i4 = *(const int4*)(Kb + (32 + cl) * KSTR + kc * 16 + hl * 8);
        s1v = __builtin_amdgcn_mfma_f32_32x32x16_bf16(a1.bf, b.bf, s1v, 0, 0, 0);
      }
    }
    __builtin_amdgcn_s_setprio(0);

    // ---- softmax (fixed max): p = exp2(s' - 14*log2e), bf16-truncated ----
    unsigned pu0[16], pu1[16];
    const int q = qw0 + cl;
    #pragma unroll
    for (int ri = 0; ri < 16; ++ri) {
      const int koff = (ri & 3) + 8 * (ri >> 2) + 4 * hl;
      bool ok0 = true, ok1 = true;
      if (needMask) {
        const int k0v = jt + koff, k1v = jt + 32 + koff;
        ok0 = (q >= k0v) && (((q - k0v) <= WIN) || (k0v < META));
        ok1 = (q >= k1v) && (((q - k1v) <= WIN) || (k1v < META));
      }
      unsigned u0 = ok0 ? (__float_as_uint(__builtin_amdgcn_exp2f(s0v[ri] - MFIX2)) & 0xFFFF0000u) : 0u;
      pu0[ri] = u0;
      lpA += __uint_as_float(u0);
      if (!isSink) {
        unsigned u1 = ok1 ? (__float_as_uint(__builtin_amdgcn_exp2f(s1v[ri] - MFIX2)) & 0xFFFF0000u) : 0u;
        pu1[ri] = u1;
        lpB += __uint_as_float(u1);
      }
    }

    // ---- PV: A = P assembled from registers (contraction order = Vts slot order) ----
    #define MKA(P, o) make_int4((P[(o)] >> 16) | P[(o)+1], (P[(o)+2] >> 16) | P[(o)+3], \
                                (P[(o)+4] >> 16) | P[(o)+5], (P[(o)+6] >> 16) | P[(o)+7])
    const int kcmax = isSink ? 1 : 4;    // sink: only keys 0..15 group can be nonzero
    __builtin_amdgcn_s_setprio(1);
    for (int kc = 0; kc < kcmax; ++kc) {
      U8 a;
      a.i4 = (kc == 0) ? MKA(pu0, 0) : (kc == 1) ? MKA(pu0, 8)
           : (kc == 2) ? MKA(pu1, 0) : MKA(pu1, 8);
      #pragma unroll
      for (int nt = 0; nt < 4; ++nt) {
        const int dim = nt * 32 + cl;
        U8 b; b.i4 = *(const int4*)(Vb + dim * VSTR + (((2 * kc + hl) ^ ((dim >> 3) & 7)) << 3));
        acc[nt] = __builtin_amdgcn_mfma_f32_32x32x16_bf16(a.bf, b.bf, acc[nt], 0, 0, 0);
      }
    }
    __builtin_amdgcn_s_setprio(0);
    #undef MKA
  }

  // ---- epilogue: l = own + partner-half partial; broadcast per q-row; store ----
  const float lp = lpA + lpB;
  const float ltot = lp + __shfl_xor(lp, 32);
  const float inv = __fdividef(1.0f, ltot);      // valid at lanes with cl = q-row
  #pragma unroll
  for (int ri = 0; ri < 16; ++ri) {
    const int rl = (ri & 3) + 8 * (ri >> 2) + 4 * hl;
    const float invq = __shfl(inv, rl, 64);      // lane rl holds 1/l for q-row rl
    #pragma unroll
    for (int nt = 0; nt < 4; ++nt) {
      Og[(size_t)(qw0 + rl) * 4096 + h * 128 + nt * 32 + cl] = acc[nt][ri] * invq;
    }
  }
}

extern "C" void kernel_launch(void* const* d_in, const int* in_sizes, int n_in,
                              void* d_out, int out_size, void* d_ws, size_t ws_size,
                              hipStream_t stream) {
  const float* Q = (const float*)d_in[0];
  const float* K = (const float*)d_in[1];
  const float* V = (const float*)d_in[2];
  float* O = (float*)d_out;
  hipLaunchKernelGGL(swa_fused, dim3(256), dim3(512), 0, stream, Q, K, V, O);
}